// Round 14
// baseline (372.262 us; speedup 1.0000x reference)
//
#include <hip/hip_runtime.h>
#include <math.h>

#define NN 50000
#define EE 800000
#define GG 64
#define FD 128
#define OUTD 10
#define GB 782          // (NN+63)/64 gemm blocks
#define BB 196          // (NN+255)/256 bounds blocks
#define NBU 196         // buckets of 256 nodes
#define NBK 128         // edge-chunk blocks
#define CH 6250         // edges per chunk (128*6250 = 800000)
#define RCAP 8          // register-carried edges per thread in k_rankfill
#define TB 64           // transpose blocks in k_histbounds
#define NPB 1954        // spmm10pool blocks: ceil(NN*OUTD/256)

typedef __attribute__((ext_vector_type(8))) short s8v;    // 8 bf16
typedef __attribute__((ext_vector_type(4))) float f4v;    // 4 f32 acc

static __device__ inline unsigned short f2b(float f) {    // f32 -> bf16 RNE
    unsigned int u = __float_as_uint(f);
    return (unsigned short)((u + 0x7FFFu + ((u >> 16) & 1u)) >> 16);
}

// ---------------- kernel 1: weight transposes || bucket histogram || bounds || zero ----------------

__global__ __launch_bounds__(256) void k_histbounds(const float* __restrict__ W1,
        const float* __restrict__ W2, const float* __restrict__ W3,
        unsigned short* __restrict__ Wt1, unsigned short* __restrict__ Wt2,
        float* __restrict__ W3t, const int* __restrict__ dst, int* __restrict__ cnt2d,
        const int* __restrict__ batch, int* __restrict__ gstart,
        float* __restrict__ sums, int* __restrict__ done) {
    int b = blockIdx.x;
    int tid = threadIdx.x;
    if (b < TB) {
        int i = b * 256 + tid;                 // [0, 16384)
        if (i < FD * FD) {
            int nn = i >> 7, k = i & 127;
            Wt1[i] = f2b(W1[k * FD + nn]);
            Wt2[i] = f2b(W2[k * FD + nn]);
        }
        if (i < FD * OUTD) {                   // W3t[col][row]
            int col = i >> 7, row = i & 127;
            W3t[i] = W3[row * OUTD + col];
        }
        if (i < GG * OUTD) sums[i] = 0.0f;     // workspace poisoned 0xAA each call
        if (i == 1024) *done = 0;
    } else if (b < TB + NBK) {
        __shared__ unsigned hist[NBU];
        int blk = b - TB;
        if (tid < NBU) hist[tid] = 0;
        __syncthreads();
        int e0 = blk * CH;
        for (int e = e0 + tid; e < e0 + CH; e += 256)
            atomicAdd(&hist[(unsigned)dst[e] >> 8], 1u);
        __syncthreads();
        if (tid < NBU) cnt2d[tid * NBK + blk] = (int)hist[tid];
    } else {
        int i = (b - TB - NBK) * 256 + tid;
        if (i < NN) {
            int bb = batch[i];
            int bp = (i == 0) ? -1 : batch[i - 1];
            for (int g = bp + 1; g <= bb; ++g) gstart[g] = i;
            if (i == NN - 1)
                for (int g = bb + 1; g <= GG; ++g) gstart[g] = NN;
        }
    }
}

// ---------------- kernel 2: scatter (replicated bucket-scan) || layer-1 GEMM ----------------

static __device__ inline void gemm_f32in_body(int bid, const float* __restrict__ A,
        const unsigned short* __restrict__ Wt, unsigned short* __restrict__ out, int n) {
    int tid = threadIdx.x;
    int wave = tid >> 6, lane = tid & 63;
    int quad = lane >> 4, c16 = lane & 15;
    int rowbase = bid * 64 + wave * 16;
    int rowA = rowbase + c16;
    if (rowA >= n) rowA = n - 1;
    f4v acc[8];
    #pragma unroll
    for (int t = 0; t < 8; ++t) acc[t] = (f4v){0.f, 0.f, 0.f, 0.f};
    #pragma unroll
    for (int k0 = 0; k0 < 128; k0 += 32) {
        const float* ap = A + (size_t)rowA * FD + k0 + quad * 8;
        float4 a0 = *(const float4*)ap;
        float4 a1 = *(const float4*)(ap + 4);
        s8v a;
        a[0] = (short)f2b(a0.x); a[1] = (short)f2b(a0.y);
        a[2] = (short)f2b(a0.z); a[3] = (short)f2b(a0.w);
        a[4] = (short)f2b(a1.x); a[5] = (short)f2b(a1.y);
        a[6] = (short)f2b(a1.z); a[7] = (short)f2b(a1.w);
        #pragma unroll
        for (int t = 0; t < 8; ++t) {
            s8v bb = *(const s8v*)(Wt + (size_t)(t * 16 + c16) * FD + k0 + quad * 8);
            acc[t] = __builtin_amdgcn_mfma_f32_16x16x32_bf16(a, bb, acc[t], 0, 0, 0);
        }
    }
    #pragma unroll
    for (int t = 0; t < 8; ++t) {
        #pragma unroll
        for (int r = 0; r < 4; ++r) {
            int row = rowbase + quad * 4 + r;
            if (row < n) out[(size_t)row * FD + t * 16 + c16] = f2b(acc[t][r]);
        }
    }
}

__global__ __launch_bounds__(256) void k_scatgemm(const int* __restrict__ src,
        const int* __restrict__ dst, const float* __restrict__ ew,
        const int* __restrict__ cnt2d, int* __restrict__ bbase_g, uint2* __restrict__ rec,
        const float* __restrict__ x, const unsigned short* __restrict__ Wt1,
        unsigned short* __restrict__ hA) {
    int b = blockIdx.x;
    int tid = threadIdx.x;
    if (b >= NBK) {                            // gemm role
        gemm_f32in_body(b - NBK, x, Wt1, hA, NN);
        return;
    }
    __shared__ int colsum[NBU];
    __shared__ int ownoff[NBU];
    __shared__ unsigned cur[NBU];
    __shared__ int wtot_s[4];
    int blk = b;
    if (tid < NBU) {
        const int* c = cnt2d + tid * NBK;
        int own = 0, tot = 0;
        for (int k = 0; k < NBK; ++k) {
            int t = c[k];
            if (k < blk) own += t;
            tot += t;
        }
        ownoff[tid] = own;
        colsum[tid] = tot;
    }
    __syncthreads();
    {
        int lane = tid & 63, wv = tid >> 6;
        int v = (tid < NBU) ? colsum[tid] : 0;
        int s = v;
        #pragma unroll
        for (int off = 1; off < 64; off <<= 1) {
            int u = __shfl_up(s, off, 64);
            if (lane >= off) s += u;
        }
        if (lane == 63) wtot_s[wv] = s;
        __syncthreads();
        int pre = 0;
        for (int j = 0; j < wv; ++j) pre += wtot_s[j];
        int base = pre + s - v;
        if (tid < NBU) {
            cur[tid] = (unsigned)(base + ownoff[tid]);
            if (blk == 0) bbase_g[tid] = base;
        }
        if (blk == 0 && tid == NBU - 1) bbase_g[NBU] = base + v;
    }
    __syncthreads();
    int e0 = blk * CH;
    for (int e = e0 + tid; e < e0 + CH; e += 256) {
        int d = dst[e];
        unsigned bkt = (unsigned)d >> 8;
        unsigned pos = atomicAdd(&cur[bkt], 1u);
        rec[pos] = make_uint2(((unsigned)(d & 255) << 16) | (unsigned)src[e],
                              __float_as_uint(ew[e]));
    }
}

// ---------------- kernel 3: merged rank+fill ----------------
// ent.y = w * dinv[dst]; self-loop ent.y = dinv[node]

__global__ __launch_bounds__(1024) void k_rankfill(const uint2* __restrict__ rec,
        const int* __restrict__ bbase, int* __restrict__ rowptr, float* __restrict__ dinv_g,
        uint2* __restrict__ ent, unsigned short* __restrict__ rankb) {
    __shared__ unsigned cntS[256];
    __shared__ float wdegS[256];
    __shared__ int wtot_s[4];
    __shared__ int rowS[256];
    __shared__ float dinvS[256];
    int b = blockIdx.x;
    int tid = threadIdx.x;
    if (tid < 256) { cntS[tid] = 0; wdegS[tid] = 0.0f; }
    __syncthreads();
    int beg = bbase[b], end = bbase[b + 1];
    int s0 = beg + tid;
    uint2 rv[RCAP];
    unsigned rk[RCAP];
    #pragma unroll
    for (int k = 0; k < RCAP; ++k) {
        int s = s0 + k * 1024;
        if (s < end) {
            uint2 r = rec[s];
            unsigned dl = r.x >> 16;
            unsigned old = atomicAdd(&cntS[dl], 1u);
            atomicAdd(&wdegS[dl], __uint_as_float(r.y));
            rv[k] = r; rk[k] = old;
        }
    }
    for (int s = s0 + RCAP * 1024; s < end; s += 1024) {
        uint2 r = rec[s];
        unsigned dl = r.x >> 16;
        unsigned old = atomicAdd(&cntS[dl], 1u);
        atomicAdd(&wdegS[dl], __uint_as_float(r.y));
        rankb[s] = (unsigned short)old;
    }
    __syncthreads();
    {
        int lane = tid & 63, wv = tid >> 6;
        int v = (tid < 256) ? (int)cntS[tid] : 0;
        int s = v;
        #pragma unroll
        for (int off = 1; off < 64; off <<= 1) {
            int u = __shfl_up(s, off, 64);
            if (lane >= off) s += u;
        }
        if (tid < 256 && lane == 63) wtot_s[wv] = s;
        __syncthreads();
        if (tid < 256) {
            int pre = 0;
            for (int j = 0; j < wv; ++j) pre += wtot_s[j];
            int excl = pre + s - v;
            int node = b * 256 + tid;
            if (node < NN) {
                int r = beg + node + excl;
                rowS[tid] = r;
                rowptr[node] = r;
                float di = 1.0f / sqrtf(wdegS[tid] + 1.0f);
                dinvS[tid] = di;
                dinv_g[node] = di;
                ent[r + v] = make_uint2((unsigned)node, __float_as_uint(di));
            }
            if (node == NN - 1) rowptr[NN] = EE + NN;
        }
    }
    __syncthreads();
    #pragma unroll
    for (int k = 0; k < RCAP; ++k) {
        int s = s0 + k * 1024;
        if (s < end) {
            uint2 r = rv[k];
            unsigned dl = r.x >> 16;
            int pos = rowS[dl] + (int)rk[k];
            float val = __uint_as_float(r.y) * dinvS[dl];
            ent[pos] = make_uint2(r.x & 0xFFFFu, __float_as_uint(val));
        }
    }
    for (int s = s0 + RCAP * 1024; s < end; s += 1024) {
        uint2 r = rec[s];
        unsigned dl = r.x >> 16;
        int pos = rowS[dl] + (int)rankb[s];
        float val = __uint_as_float(r.y) * dinvS[dl];
        ent[pos] = make_uint2(r.x & 0xFFFFu, __float_as_uint(val));
    }
}

// ---------------- layer-1 spmm: per-edge dinv[src] (hA unscaled); output pre-scaled by dinv[w] ----------------

__global__ __launch_bounds__(256) void k_spmm_bf(const int* __restrict__ rowptr,
        const uint2* __restrict__ ent, const float* __restrict__ dinv,
        const unsigned short* __restrict__ tin, const float* __restrict__ bias,
        unsigned short* __restrict__ out, int n) {
    int w = (blockIdx.x * blockDim.x + threadIdx.x) >> 6;
    int lane = threadIdx.x & 63;
    if (w >= n) return;
    int c = lane & 15, g = lane >> 4;
    int beg = rowptr[w], end = rowptr[w + 1];
    float acc[8];
    #pragma unroll
    for (int j = 0; j < 8; ++j) acc[j] = 0.0f;
    int e0 = beg;
    for (; e0 + 16 <= end; e0 += 16) {
        uint2 en[4];
        float dv[4];
        uint4 t[4];
        #pragma unroll
        for (int u = 0; u < 4; ++u) en[u] = ent[e0 + 4 * u + g];
        #pragma unroll
        for (int u = 0; u < 4; ++u) dv[u] = dinv[en[u].x];
        #pragma unroll
        for (int u = 0; u < 4; ++u)
            t[u] = *(const uint4*)(tin + (size_t)en[u].x * FD + c * 8);
        #pragma unroll
        for (int u = 0; u < 4; ++u) {
            float v = __uint_as_float(en[u].y) * dv[u];
            acc[0] += v * __uint_as_float(t[u].x << 16);
            acc[1] += v * __uint_as_float(t[u].x & 0xFFFF0000u);
            acc[2] += v * __uint_as_float(t[u].y << 16);
            acc[3] += v * __uint_as_float(t[u].y & 0xFFFF0000u);
            acc[4] += v * __uint_as_float(t[u].z << 16);
            acc[5] += v * __uint_as_float(t[u].z & 0xFFFF0000u);
            acc[6] += v * __uint_as_float(t[u].w << 16);
            acc[7] += v * __uint_as_float(t[u].w & 0xFFFF0000u);
        }
    }
    for (; e0 < end; e0 += 4) {
        int e = e0 + g;
        uint2 en = (e < end) ? ent[e] : make_uint2(0u, 0u);
        float v = (e < end) ? __uint_as_float(en.y) * dinv[en.x] : 0.0f;
        uint4 t = *(const uint4*)(tin + (size_t)en.x * FD + c * 8);
        acc[0] += v * __uint_as_float(t.x << 16);
        acc[1] += v * __uint_as_float(t.x & 0xFFFF0000u);
        acc[2] += v * __uint_as_float(t.y << 16);
        acc[3] += v * __uint_as_float(t.y & 0xFFFF0000u);
        acc[4] += v * __uint_as_float(t.z << 16);
        acc[5] += v * __uint_as_float(t.z & 0xFFFF0000u);
        acc[6] += v * __uint_as_float(t.w << 16);
        acc[7] += v * __uint_as_float(t.w & 0xFFFF0000u);
    }
    #pragma unroll
    for (int j = 0; j < 8; ++j) {
        acc[j] += __shfl_xor(acc[j], 16, 64);
        acc[j] += __shfl_xor(acc[j], 32, 64);
    }
    if (g == 0) {
        float dself = dinv[w];                 // pre-scale h1 so downstream drops dinv[src]
        uint4 r;
        float o[8];
        #pragma unroll
        for (int j = 0; j < 8; ++j)
            o[j] = fmaxf(acc[j] + bias[c * 8 + j], 0.0f) * dself;
        r.x = (unsigned)f2b(o[0]) | ((unsigned)f2b(o[1]) << 16);
        r.y = (unsigned)f2b(o[2]) | ((unsigned)f2b(o[3]) << 16);
        r.z = (unsigned)f2b(o[4]) | ((unsigned)f2b(o[5]) << 16);
        r.w = (unsigned)f2b(o[6]) | ((unsigned)f2b(o[7]) << 16);
        *(uint4*)(out + (size_t)w * FD + c * 8) = r;
    }
}

// ---------------- dense transform: bf16 MFMA GEMM (bf16 in) ----------------

__global__ __launch_bounds__(256) void k_gemm_bf(const unsigned short* __restrict__ A,
        const unsigned short* __restrict__ Wt, unsigned short* __restrict__ out, int n) {
    int tid = threadIdx.x;
    int wave = tid >> 6, lane = tid & 63;
    int quad = lane >> 4, c16 = lane & 15;
    int rowbase = blockIdx.x * 64 + wave * 16;
    int rowA = rowbase + c16;
    if (rowA >= n) rowA = n - 1;
    f4v acc[8];
    #pragma unroll
    for (int t = 0; t < 8; ++t) acc[t] = (f4v){0.f, 0.f, 0.f, 0.f};
    #pragma unroll
    for (int k0 = 0; k0 < 128; k0 += 32) {
        s8v a = *(const s8v*)(A + (size_t)rowA * FD + k0 + quad * 8);
        #pragma unroll
        for (int t = 0; t < 8; ++t) {
            s8v b = *(const s8v*)(Wt + (size_t)(t * 16 + c16) * FD + k0 + quad * 8);
            acc[t] = __builtin_amdgcn_mfma_f32_16x16x32_bf16(a, b, acc[t], 0, 0, 0);
        }
    }
    #pragma unroll
    for (int t = 0; t < 8; ++t) {
        #pragma unroll
        for (int r = 0; r < 4; ++r) {
            int row = rowbase + quad * 4 + r;
            if (row < n) out[(size_t)row * FD + t * 16 + c16] = f2b(acc[t][r]);
        }
    }
}

// ---------------- layer-2 aggregation + relu + W3t epilogue (input pre-scaled; no per-edge dinv) ----------------
// output bufC pre-scaled by dinv[w] so layer-3 drops dinv too.

__global__ __launch_bounds__(256) void k_spmm_w3(const int* __restrict__ rowptr,
        const uint2* __restrict__ ent, const float* __restrict__ dinv,
        const unsigned short* __restrict__ tin, const float* __restrict__ bias2,
        const float* __restrict__ W3t, float* __restrict__ outc, int n) {
    int tid = threadIdx.x;
    int w = (blockIdx.x * blockDim.x + tid) >> 6;
    int lane = tid & 63;
    if (w >= n) return;
    int c = lane & 15, g = lane >> 4;
    int beg = rowptr[w], end = rowptr[w + 1];
    float acc[8];
    #pragma unroll
    for (int j = 0; j < 8; ++j) acc[j] = 0.0f;
    int e0 = beg;
    for (; e0 + 16 <= end; e0 += 16) {
        uint2 en[4];
        uint4 t[4];
        #pragma unroll
        for (int u = 0; u < 4; ++u) en[u] = ent[e0 + 4 * u + g];
        #pragma unroll
        for (int u = 0; u < 4; ++u)
            t[u] = *(const uint4*)(tin + (size_t)en[u].x * FD + c * 8);
        #pragma unroll
        for (int u = 0; u < 4; ++u) {
            float v = __uint_as_float(en[u].y);
            acc[0] += v * __uint_as_float(t[u].x << 16);
            acc[1] += v * __uint_as_float(t[u].x & 0xFFFF0000u);
            acc[2] += v * __uint_as_float(t[u].y << 16);
            acc[3] += v * __uint_as_float(t[u].y & 0xFFFF0000u);
            acc[4] += v * __uint_as_float(t[u].z << 16);
            acc[5] += v * __uint_as_float(t[u].z & 0xFFFF0000u);
            acc[6] += v * __uint_as_float(t[u].w << 16);
            acc[7] += v * __uint_as_float(t[u].w & 0xFFFF0000u);
        }
    }
    for (; e0 < end; e0 += 4) {
        int e = e0 + g;
        uint2 en = (e < end) ? ent[e] : make_uint2(0u, 0u);
        float v = (e < end) ? __uint_as_float(en.y) : 0.0f;
        uint4 t = *(const uint4*)(tin + (size_t)en.x * FD + c * 8);
        acc[0] += v * __uint_as_float(t.x << 16);
        acc[1] += v * __uint_as_float(t.x & 0xFFFF0000u);
        acc[2] += v * __uint_as_float(t.y << 16);
        acc[3] += v * __uint_as_float(t.y & 0xFFFF0000u);
        acc[4] += v * __uint_as_float(t.z << 16);
        acc[5] += v * __uint_as_float(t.z & 0xFFFF0000u);
        acc[6] += v * __uint_as_float(t.w << 16);
        acc[7] += v * __uint_as_float(t.w & 0xFFFF0000u);
    }
    #pragma unroll
    for (int j = 0; j < 8; ++j) {      // butterfly: ALL lanes get full sums
        acc[j] += __shfl_xor(acc[j], 16, 64);
        acc[j] += __shfl_xor(acc[j], 32, 64);
    }
    float b2r[8], o[8];
    *(float4*)&b2r[0] = *(const float4*)(bias2 + c * 8);
    *(float4*)&b2r[4] = *(const float4*)(bias2 + c * 8 + 4);
    #pragma unroll
    for (int j = 0; j < 8; ++j)
        o[j] = fmaxf(acc[j] + b2r[j], 0.0f);
    float w0[8], w1[8];
    *(float4*)&w0[0] = *(const float4*)(W3t + g * FD + c * 8);
    *(float4*)&w0[4] = *(const float4*)(W3t + g * FD + c * 8 + 4);
    *(float4*)&w1[0] = *(const float4*)(W3t + (g + 4) * FD + c * 8);
    *(float4*)&w1[4] = *(const float4*)(W3t + (g + 4) * FD + c * 8 + 4);
    float p0 = 0.0f, p1 = 0.0f, p2 = 0.0f;
    #pragma unroll
    for (int j = 0; j < 8; ++j) {
        p0 += o[j] * w0[j];
        p1 += o[j] * w1[j];
    }
    if (g < 2) {
        float w2[8];
        *(float4*)&w2[0] = *(const float4*)(W3t + (g + 8) * FD + c * 8);
        *(float4*)&w2[4] = *(const float4*)(W3t + (g + 8) * FD + c * 8 + 4);
        #pragma unroll
        for (int j = 0; j < 8; ++j) p2 += o[j] * w2[j];
    }
    #pragma unroll
    for (int off = 1; off < 16; off <<= 1) {
        p0 += __shfl_xor(p0, off, 64);
        p1 += __shfl_xor(p1, off, 64);
        p2 += __shfl_xor(p2, off, 64);
    }
    if (c == 0) {
        float dself = dinv[w];                 // pre-scale bufC for layer-3
        float* op = outc + (size_t)w * OUTD;
        op[g] = p0 * dself;
        op[g + 4] = p1 * dself;
        if (g < 2) op[g + 8] = p2 * dself;
    }
}

// ---------------- layer-3 aggregation + pooling + log_softmax (last-block ticket) ----------------

__global__ __launch_bounds__(256) void k_spmm10pool(const int* __restrict__ rowptr,
        const uint2* __restrict__ ent, const float* __restrict__ tin,
        const float* __restrict__ bias, const int* __restrict__ batch,
        const int* __restrict__ gstart, float* __restrict__ sums, int* __restrict__ done,
        float* __restrict__ out) {
    __shared__ float gs[16][OUTD];
    __shared__ int gmin_s, gmax_s, last_s;
    int tid = threadIdx.x;
    int t = blockIdx.x * 256 + tid;
    int node = t / OUTD;
    int c = t - node * OUTD;
    bool act = node < NN;
    if (tid == 0) { gmin_s = 0x7fffffff; gmax_s = -1; }
    if (tid < 16 * OUTD) gs[tid / OUTD][tid % OUTD] = 0.0f;
    __syncthreads();
    int g = 0;
    float val = 0.0f;
    if (act) {
        g = batch[node];
        atomicMin(&gmin_s, g);
        atomicMax(&gmax_s, g);
        int beg = rowptr[node], end = rowptr[node + 1];
        for (int e = beg; e < end; ++e) {
            uint2 en = ent[e];
            val += __uint_as_float(en.y) * tin[(size_t)en.x * OUTD + c];
        }
        val += bias[c];
    }
    __syncthreads();
    if (act) atomicAdd(&gs[g & 15][c], val);
    __syncthreads();
    if (tid < 16 * OUTD) {
        int s = tid / OUTD, cc = tid - s * OUTD;
        int gmin = gmin_s, gmax = gmax_s;
        if (gmax >= 0) {
            int gg = gmin + ((s - (gmin & 15) + 16) & 15);
            if (gg <= gmax) atomicAdd(&sums[gg * OUTD + cc], gs[s][cc]);
        }
    }
    __threadfence();
    __syncthreads();
    if (tid == 0) last_s = (atomicAdd(done, 1) == NPB - 1) ? 1 : 0;
    __syncthreads();
    if (last_s && tid < GG) {
        int g2 = tid;
        float cf = fmaxf((float)(gstart[g2 + 1] - gstart[g2]), 1.0f);
        float v[OUTD], m = -1e30f;
        #pragma unroll
        for (int cc = 0; cc < OUTD; ++cc) {
            float s = __hip_atomic_load(&sums[g2 * OUTD + cc], __ATOMIC_RELAXED,
                                        __HIP_MEMORY_SCOPE_AGENT);
            v[cc] = s / cf;
            m = fmaxf(m, v[cc]);
        }
        float s = 0.0f;
        #pragma unroll
        for (int cc = 0; cc < OUTD; ++cc) s += expf(v[cc] - m);
        float l = logf(s);
        #pragma unroll
        for (int cc = 0; cc < OUTD; ++cc) out[g2 * OUTD + cc] = v[cc] - m - l;
    }
}

// ---------------- launcher ----------------

extern "C" void kernel_launch(void* const* d_in, const int* in_sizes, int n_in,
                              void* d_out, int out_size, void* d_ws, size_t ws_size,
                              hipStream_t stream) {
    const float* x   = (const float*)d_in[0];
    const int*   ei  = (const int*)d_in[1];
    const float* ew  = (const float*)d_in[2];
    const int*   bat = (const int*)d_in[3];
    const float* W1  = (const float*)d_in[4];
    const float* b1  = (const float*)d_in[5];
    const float* W2  = (const float*)d_in[6];
    const float* b2  = (const float*)d_in[7];
    const float* W3  = (const float*)d_in[8];
    const float* b3  = (const float*)d_in[9];
    float* out = (float*)d_out;

    const int* src = ei;
    const int* dst = ei + EE;

    char* p = (char*)d_ws;
    auto alloc = [&](size_t bytes) -> void* {
        void* r = (void*)p;
        p += (bytes + 255) & ~(size_t)255;
        return r;
    };
    int*            cnt2d  = (int*)  alloc((size_t)NBU * NBK * 4);
    int*            bbase  = (int*)  alloc((size_t)(NBU + 1) * 4);
    uint2*          rec    = (uint2*)alloc((size_t)EE * 8);
    unsigned short* rankb  = (unsigned short*)alloc((size_t)EE * 2);
    float*          dinv   = (float*)alloc((size_t)NN * 4);
    int*            rowptr = (int*)  alloc((size_t)(NN + 1) * 4);
    uint2*          ent    = (uint2*)alloc((size_t)(EE + NN) * 8);
    unsigned short* Wt1    = (unsigned short*)alloc((size_t)FD * FD * 2);
    unsigned short* Wt2    = (unsigned short*)alloc((size_t)FD * FD * 2);
    float*          W3t    = (float*)alloc((size_t)FD * OUTD * 4);
    unsigned short* hA     = (unsigned short*)alloc((size_t)NN * FD * 2);
    unsigned short* hB     = (unsigned short*)alloc((size_t)NN * FD * 2);
    float*          bufC   = (float*)alloc((size_t)NN * OUTD * 4);
    float*          sums   = (float*)alloc((size_t)GG * OUTD * 4);
    int*            done   = (int*)  alloc(256);
    int*            gstart = (int*)  alloc((size_t)(GG + 1) * 4);
    (void)ws_size; (void)in_sizes; (void)n_in; (void)out_size;

    const int B = 256;
    // 1: transposes || bucket histogram || graph bounds || zero sums/done
    k_histbounds<<<TB + NBK + BB, B, 0, stream>>>(W1, W2, W3, Wt1, Wt2, W3t,
                                                  dst, cnt2d, bat, gstart, sums, done);
    // 2: scatter (bucket-segmented records) || layer-1 GEMM
    k_scatgemm  <<<NBK + GB, B, 0, stream>>>(src, dst, ew, cnt2d, bbase, rec, x, Wt1, hA);
    // 3: rank+fill: rowptr + dinv + full CSR
    k_rankfill  <<<NBU, 1024, 0, stream>>>(rec, bbase, rowptr, dinv, ent, rankb);
    // 4: layer-1 aggregation (output pre-scaled by dinv)
    k_spmm_bf   <<<(NN * 64 + B - 1) / B, B, 0, stream>>>(rowptr, ent, dinv, hA, b1, hB, NN);
    // 5: layer-2 transform
    k_gemm_bf   <<<GB, B, 0, stream>>>(hB, Wt2, hA, NN);
    // 6: layer-2 aggregation + relu + W3 (output pre-scaled by dinv)
    k_spmm_w3   <<<(NN * 64 + B - 1) / B, B, 0, stream>>>(rowptr, ent, dinv, hA, b2, W3t, bufC, NN);
    // 7: layer-3 aggregation + pool + log_softmax
    k_spmm10pool<<<NPB, B, 0, stream>>>(rowptr, ent, bufC, b3, bat, gstart, sums, done, out);
}

// Round 15
// 254.787 us; speedup vs baseline: 1.4611x; 1.4611x over previous
//
#include <hip/hip_runtime.h>
#include <math.h>

#define NN 50000
#define EE 800000
#define GG 64
#define FD 128
#define OUTD 10
#define GB 782          // (NN+63)/64 gemm blocks
#define BB 196          // (NN+255)/256 bounds blocks
#define NBU 196         // buckets of 256 nodes
#define NBK 128         // edge-chunk blocks
#define CH 6250         // edges per chunk (128*6250 = 800000)
#define RCAP 8          // register-carried edges per thread in k_rankfill
#define TB 64           // transpose blocks in k_histbounds

typedef __attribute__((ext_vector_type(8))) short s8v;    // 8 bf16
typedef __attribute__((ext_vector_type(4))) float f4v;    // 4 f32 acc

static __device__ inline unsigned short f2b(float f) {    // f32 -> bf16 RNE
    unsigned int u = __float_as_uint(f);
    return (unsigned short)((u + 0x7FFFu + ((u >> 16) & 1u)) >> 16);
}

// ---------------- kernel 1: weight transposes || bucket histogram || bounds ----------------

__global__ __launch_bounds__(256) void k_histbounds(const float* __restrict__ W1,
        const float* __restrict__ W2, const float* __restrict__ W3,
        unsigned short* __restrict__ Wt1, unsigned short* __restrict__ Wt2,
        float* __restrict__ W3t, const int* __restrict__ dst, int* __restrict__ cnt2d,
        const int* __restrict__ batch, int* __restrict__ gstart) {
    int b = blockIdx.x;
    int tid = threadIdx.x;
    if (b < TB) {
        int i = b * 256 + tid;                 // [0, 16384)
        if (i < FD * FD) {
            int nn = i >> 7, k = i & 127;
            Wt1[i] = f2b(W1[k * FD + nn]);
            Wt2[i] = f2b(W2[k * FD + nn]);
        }
        if (i < FD * OUTD) {                   // W3t[col][row]
            int col = i >> 7, row = i & 127;
            W3t[i] = W3[row * OUTD + col];
        }
    } else if (b < TB + NBK) {
        __shared__ unsigned hist[NBU];
        int blk = b - TB;
        if (tid < NBU) hist[tid] = 0;
        __syncthreads();
        int e0 = blk * CH;
        for (int e = e0 + tid; e < e0 + CH; e += 256)
            atomicAdd(&hist[(unsigned)dst[e] >> 8], 1u);
        __syncthreads();
        if (tid < NBU) cnt2d[tid * NBK + blk] = (int)hist[tid];
    } else {
        int i = (b - TB - NBK) * 256 + tid;
        if (i < NN) {
            int bb = batch[i];
            int bp = (i == 0) ? -1 : batch[i - 1];
            for (int g = bp + 1; g <= bb; ++g) gstart[g] = i;
            if (i == NN - 1)
                for (int g = bb + 1; g <= GG; ++g) gstart[g] = NN;
        }
    }
}

// ---------------- kernel 2: scatter (replicated bucket-scan) || layer-1 GEMM ----------------

static __device__ inline void gemm_f32in_body(int bid, const float* __restrict__ A,
        const unsigned short* __restrict__ Wt, unsigned short* __restrict__ out, int n) {
    int tid = threadIdx.x;
    int wave = tid >> 6, lane = tid & 63;
    int quad = lane >> 4, c16 = lane & 15;
    int rowbase = bid * 64 + wave * 16;
    int rowA = rowbase + c16;
    if (rowA >= n) rowA = n - 1;
    f4v acc[8];
    #pragma unroll
    for (int t = 0; t < 8; ++t) acc[t] = (f4v){0.f, 0.f, 0.f, 0.f};
    #pragma unroll
    for (int k0 = 0; k0 < 128; k0 += 32) {
        const float* ap = A + (size_t)rowA * FD + k0 + quad * 8;
        float4 a0 = *(const float4*)ap;
        float4 a1 = *(const float4*)(ap + 4);
        s8v a;
        a[0] = (short)f2b(a0.x); a[1] = (short)f2b(a0.y);
        a[2] = (short)f2b(a0.z); a[3] = (short)f2b(a0.w);
        a[4] = (short)f2b(a1.x); a[5] = (short)f2b(a1.y);
        a[6] = (short)f2b(a1.z); a[7] = (short)f2b(a1.w);
        #pragma unroll
        for (int t = 0; t < 8; ++t) {
            s8v bb = *(const s8v*)(Wt + (size_t)(t * 16 + c16) * FD + k0 + quad * 8);
            acc[t] = __builtin_amdgcn_mfma_f32_16x16x32_bf16(a, bb, acc[t], 0, 0, 0);
        }
    }
    #pragma unroll
    for (int t = 0; t < 8; ++t) {
        #pragma unroll
        for (int r = 0; r < 4; ++r) {
            int row = rowbase + quad * 4 + r;
            if (row < n) out[(size_t)row * FD + t * 16 + c16] = f2b(acc[t][r]);
        }
    }
}

__global__ __launch_bounds__(256) void k_scatgemm(const int* __restrict__ src,
        const int* __restrict__ dst, const float* __restrict__ ew,
        const int* __restrict__ cnt2d, int* __restrict__ bbase_g, uint2* __restrict__ rec,
        const float* __restrict__ x, const unsigned short* __restrict__ Wt1,
        unsigned short* __restrict__ hA) {
    int b = blockIdx.x;
    int tid = threadIdx.x;
    if (b >= NBK) {                            // gemm role
        gemm_f32in_body(b - NBK, x, Wt1, hA, NN);
        return;
    }
    __shared__ int colsum[NBU];
    __shared__ int ownoff[NBU];
    __shared__ unsigned cur[NBU];
    __shared__ int wtot_s[4];
    int blk = b;
    if (tid < NBU) {
        const int* c = cnt2d + tid * NBK;
        int own = 0, tot = 0;
        for (int k = 0; k < NBK; ++k) {
            int t = c[k];
            if (k < blk) own += t;
            tot += t;
        }
        ownoff[tid] = own;
        colsum[tid] = tot;
    }
    __syncthreads();
    {
        int lane = tid & 63, wv = tid >> 6;
        int v = (tid < NBU) ? colsum[tid] : 0;
        int s = v;
        #pragma unroll
        for (int off = 1; off < 64; off <<= 1) {
            int u = __shfl_up(s, off, 64);
            if (lane >= off) s += u;
        }
        if (lane == 63) wtot_s[wv] = s;
        __syncthreads();
        int pre = 0;
        for (int j = 0; j < wv; ++j) pre += wtot_s[j];
        int base = pre + s - v;
        if (tid < NBU) {
            cur[tid] = (unsigned)(base + ownoff[tid]);
            if (blk == 0) bbase_g[tid] = base;
        }
        if (blk == 0 && tid == NBU - 1) bbase_g[NBU] = base + v;
    }
    __syncthreads();
    int e0 = blk * CH;
    for (int e = e0 + tid; e < e0 + CH; e += 256) {
        int d = dst[e];
        unsigned bkt = (unsigned)d >> 8;
        unsigned pos = atomicAdd(&cur[bkt], 1u);
        rec[pos] = make_uint2(((unsigned)(d & 255) << 16) | (unsigned)src[e],
                              __float_as_uint(ew[e]));
    }
}

// ---------------- kernel 3: merged rank+fill ----------------
// ent.y = w * dinv[dst]; self-loop ent.y = dinv[node]

__global__ __launch_bounds__(1024) void k_rankfill(const uint2* __restrict__ rec,
        const int* __restrict__ bbase, int* __restrict__ rowptr, float* __restrict__ dinv_g,
        uint2* __restrict__ ent, unsigned short* __restrict__ rankb) {
    __shared__ unsigned cntS[256];
    __shared__ float wdegS[256];
    __shared__ int wtot_s[4];
    __shared__ int rowS[256];
    __shared__ float dinvS[256];
    int b = blockIdx.x;
    int tid = threadIdx.x;
    if (tid < 256) { cntS[tid] = 0; wdegS[tid] = 0.0f; }
    __syncthreads();
    int beg = bbase[b], end = bbase[b + 1];
    int s0 = beg + tid;
    uint2 rv[RCAP];
    unsigned rk[RCAP];
    #pragma unroll
    for (int k = 0; k < RCAP; ++k) {
        int s = s0 + k * 1024;
        if (s < end) {
            uint2 r = rec[s];
            unsigned dl = r.x >> 16;
            unsigned old = atomicAdd(&cntS[dl], 1u);
            atomicAdd(&wdegS[dl], __uint_as_float(r.y));
            rv[k] = r; rk[k] = old;
        }
    }
    for (int s = s0 + RCAP * 1024; s < end; s += 1024) {
        uint2 r = rec[s];
        unsigned dl = r.x >> 16;
        unsigned old = atomicAdd(&cntS[dl], 1u);
        atomicAdd(&wdegS[dl], __uint_as_float(r.y));
        rankb[s] = (unsigned short)old;
    }
    __syncthreads();
    {
        int lane = tid & 63, wv = tid >> 6;
        int v = (tid < 256) ? (int)cntS[tid] : 0;
        int s = v;
        #pragma unroll
        for (int off = 1; off < 64; off <<= 1) {
            int u = __shfl_up(s, off, 64);
            if (lane >= off) s += u;
        }
        if (tid < 256 && lane == 63) wtot_s[wv] = s;
        __syncthreads();
        if (tid < 256) {
            int pre = 0;
            for (int j = 0; j < wv; ++j) pre += wtot_s[j];
            int excl = pre + s - v;
            int node = b * 256 + tid;
            if (node < NN) {
                int r = beg + node + excl;
                rowS[tid] = r;
                rowptr[node] = r;
                float di = 1.0f / sqrtf(wdegS[tid] + 1.0f);
                dinvS[tid] = di;
                dinv_g[node] = di;
                ent[r + v] = make_uint2((unsigned)node, __float_as_uint(di));
            }
            if (node == NN - 1) rowptr[NN] = EE + NN;
        }
    }
    __syncthreads();
    #pragma unroll
    for (int k = 0; k < RCAP; ++k) {
        int s = s0 + k * 1024;
        if (s < end) {
            uint2 r = rv[k];
            unsigned dl = r.x >> 16;
            int pos = rowS[dl] + (int)rk[k];
            float val = __uint_as_float(r.y) * dinvS[dl];
            ent[pos] = make_uint2(r.x & 0xFFFFu, __float_as_uint(val));
        }
    }
    for (int s = s0 + RCAP * 1024; s < end; s += 1024) {
        uint2 r = rec[s];
        unsigned dl = r.x >> 16;
        int pos = rowS[dl] + (int)rankb[s];
        float val = __uint_as_float(r.y) * dinvS[dl];
        ent[pos] = make_uint2(r.x & 0xFFFFu, __float_as_uint(val));
    }
}

// ---------------- layer-1 spmm: per-edge dinv[src]; output pre-scaled by dinv[w] ----------------

__global__ __launch_bounds__(256) void k_spmm_bf(const int* __restrict__ rowptr,
        const uint2* __restrict__ ent, const float* __restrict__ dinv,
        const unsigned short* __restrict__ tin, const float* __restrict__ bias,
        unsigned short* __restrict__ out, int n) {
    int w = (blockIdx.x * blockDim.x + threadIdx.x) >> 6;
    int lane = threadIdx.x & 63;
    if (w >= n) return;
    int c = lane & 15, g = lane >> 4;
    int beg = rowptr[w], end = rowptr[w + 1];
    float acc[8];
    #pragma unroll
    for (int j = 0; j < 8; ++j) acc[j] = 0.0f;
    int e0 = beg;
    for (; e0 + 16 <= end; e0 += 16) {
        uint2 en[4];
        float dv[4];
        uint4 t[4];
        #pragma unroll
        for (int u = 0; u < 4; ++u) en[u] = ent[e0 + 4 * u + g];
        #pragma unroll
        for (int u = 0; u < 4; ++u) dv[u] = dinv[en[u].x];
        #pragma unroll
        for (int u = 0; u < 4; ++u)
            t[u] = *(const uint4*)(tin + (size_t)en[u].x * FD + c * 8);
        #pragma unroll
        for (int u = 0; u < 4; ++u) {
            float v = __uint_as_float(en[u].y) * dv[u];
            acc[0] += v * __uint_as_float(t[u].x << 16);
            acc[1] += v * __uint_as_float(t[u].x & 0xFFFF0000u);
            acc[2] += v * __uint_as_float(t[u].y << 16);
            acc[3] += v * __uint_as_float(t[u].y & 0xFFFF0000u);
            acc[4] += v * __uint_as_float(t[u].z << 16);
            acc[5] += v * __uint_as_float(t[u].z & 0xFFFF0000u);
            acc[6] += v * __uint_as_float(t[u].w << 16);
            acc[7] += v * __uint_as_float(t[u].w & 0xFFFF0000u);
        }
    }
    for (; e0 < end; e0 += 4) {
        int e = e0 + g;
        uint2 en = (e < end) ? ent[e] : make_uint2(0u, 0u);
        float v = (e < end) ? __uint_as_float(en.y) * dinv[en.x] : 0.0f;
        uint4 t = *(const uint4*)(tin + (size_t)en.x * FD + c * 8);
        acc[0] += v * __uint_as_float(t.x << 16);
        acc[1] += v * __uint_as_float(t.x & 0xFFFF0000u);
        acc[2] += v * __uint_as_float(t.y << 16);
        acc[3] += v * __uint_as_float(t.y & 0xFFFF0000u);
        acc[4] += v * __uint_as_float(t.z << 16);
        acc[5] += v * __uint_as_float(t.z & 0xFFFF0000u);
        acc[6] += v * __uint_as_float(t.w << 16);
        acc[7] += v * __uint_as_float(t.w & 0xFFFF0000u);
    }
    #pragma unroll
    for (int j = 0; j < 8; ++j) {
        acc[j] += __shfl_xor(acc[j], 16, 64);
        acc[j] += __shfl_xor(acc[j], 32, 64);
    }
    if (g == 0) {
        float dself = dinv[w];                 // pre-scale h1 so downstream drops dinv[src]
        uint4 r;
        float o[8];
        #pragma unroll
        for (int j = 0; j < 8; ++j)
            o[j] = fmaxf(acc[j] + bias[c * 8 + j], 0.0f) * dself;
        r.x = (unsigned)f2b(o[0]) | ((unsigned)f2b(o[1]) << 16);
        r.y = (unsigned)f2b(o[2]) | ((unsigned)f2b(o[3]) << 16);
        r.z = (unsigned)f2b(o[4]) | ((unsigned)f2b(o[5]) << 16);
        r.w = (unsigned)f2b(o[6]) | ((unsigned)f2b(o[7]) << 16);
        *(uint4*)(out + (size_t)w * FD + c * 8) = r;
    }
}

// ---------------- dense transform: bf16 MFMA GEMM (bf16 in) ----------------

__global__ __launch_bounds__(256) void k_gemm_bf(const unsigned short* __restrict__ A,
        const unsigned short* __restrict__ Wt, unsigned short* __restrict__ out, int n) {
    int tid = threadIdx.x;
    int wave = tid >> 6, lane = tid & 63;
    int quad = lane >> 4, c16 = lane & 15;
    int rowbase = blockIdx.x * 64 + wave * 16;
    int rowA = rowbase + c16;
    if (rowA >= n) rowA = n - 1;
    f4v acc[8];
    #pragma unroll
    for (int t = 0; t < 8; ++t) acc[t] = (f4v){0.f, 0.f, 0.f, 0.f};
    #pragma unroll
    for (int k0 = 0; k0 < 128; k0 += 32) {
        s8v a = *(const s8v*)(A + (size_t)rowA * FD + k0 + quad * 8);
        #pragma unroll
        for (int t = 0; t < 8; ++t) {
            s8v b = *(const s8v*)(Wt + (size_t)(t * 16 + c16) * FD + k0 + quad * 8);
            acc[t] = __builtin_amdgcn_mfma_f32_16x16x32_bf16(a, b, acc[t], 0, 0, 0);
        }
    }
    #pragma unroll
    for (int t = 0; t < 8; ++t) {
        #pragma unroll
        for (int r = 0; r < 4; ++r) {
            int row = rowbase + quad * 4 + r;
            if (row < n) out[(size_t)row * FD + t * 16 + c16] = f2b(acc[t][r]);
        }
    }
}

// ---------------- layer-2 aggregation + relu + W3t epilogue (no per-edge dinv) ----------------
// output bufC pre-scaled by dinv[w] so layer-3 drops dinv too.

__global__ __launch_bounds__(256) void k_spmm_w3(const int* __restrict__ rowptr,
        const uint2* __restrict__ ent, const float* __restrict__ dinv,
        const unsigned short* __restrict__ tin, const float* __restrict__ bias2,
        const float* __restrict__ W3t, float* __restrict__ outc, int n) {
    int tid = threadIdx.x;
    int w = (blockIdx.x * blockDim.x + tid) >> 6;
    int lane = tid & 63;
    if (w >= n) return;
    int c = lane & 15, g = lane >> 4;
    int beg = rowptr[w], end = rowptr[w + 1];
    float acc[8];
    #pragma unroll
    for (int j = 0; j < 8; ++j) acc[j] = 0.0f;
    int e0 = beg;
    for (; e0 + 16 <= end; e0 += 16) {
        uint2 en[4];
        uint4 t[4];
        #pragma unroll
        for (int u = 0; u < 4; ++u) en[u] = ent[e0 + 4 * u + g];
        #pragma unroll
        for (int u = 0; u < 4; ++u)
            t[u] = *(const uint4*)(tin + (size_t)en[u].x * FD + c * 8);
        #pragma unroll
        for (int u = 0; u < 4; ++u) {
            float v = __uint_as_float(en[u].y);
            acc[0] += v * __uint_as_float(t[u].x << 16);
            acc[1] += v * __uint_as_float(t[u].x & 0xFFFF0000u);
            acc[2] += v * __uint_as_float(t[u].y << 16);
            acc[3] += v * __uint_as_float(t[u].y & 0xFFFF0000u);
            acc[4] += v * __uint_as_float(t[u].z << 16);
            acc[5] += v * __uint_as_float(t[u].z & 0xFFFF0000u);
            acc[6] += v * __uint_as_float(t[u].w << 16);
            acc[7] += v * __uint_as_float(t[u].w & 0xFFFF0000u);
        }
    }
    for (; e0 < end; e0 += 4) {
        int e = e0 + g;
        uint2 en = (e < end) ? ent[e] : make_uint2(0u, 0u);
        float v = (e < end) ? __uint_as_float(en.y) : 0.0f;
        uint4 t = *(const uint4*)(tin + (size_t)en.x * FD + c * 8);
        acc[0] += v * __uint_as_float(t.x << 16);
        acc[1] += v * __uint_as_float(t.x & 0xFFFF0000u);
        acc[2] += v * __uint_as_float(t.y << 16);
        acc[3] += v * __uint_as_float(t.y & 0xFFFF0000u);
        acc[4] += v * __uint_as_float(t.z << 16);
        acc[5] += v * __uint_as_float(t.z & 0xFFFF0000u);
        acc[6] += v * __uint_as_float(t.w << 16);
        acc[7] += v * __uint_as_float(t.w & 0xFFFF0000u);
    }
    #pragma unroll
    for (int j = 0; j < 8; ++j) {      // butterfly: ALL lanes get full sums
        acc[j] += __shfl_xor(acc[j], 16, 64);
        acc[j] += __shfl_xor(acc[j], 32, 64);
    }
    float b2r[8], o[8];
    *(float4*)&b2r[0] = *(const float4*)(bias2 + c * 8);
    *(float4*)&b2r[4] = *(const float4*)(bias2 + c * 8 + 4);
    #pragma unroll
    for (int j = 0; j < 8; ++j)
        o[j] = fmaxf(acc[j] + b2r[j], 0.0f);
    float w0[8], w1[8];
    *(float4*)&w0[0] = *(const float4*)(W3t + g * FD + c * 8);
    *(float4*)&w0[4] = *(const float4*)(W3t + g * FD + c * 8 + 4);
    *(float4*)&w1[0] = *(const float4*)(W3t + (g + 4) * FD + c * 8);
    *(float4*)&w1[4] = *(const float4*)(W3t + (g + 4) * FD + c * 8 + 4);
    float p0 = 0.0f, p1 = 0.0f, p2 = 0.0f;
    #pragma unroll
    for (int j = 0; j < 8; ++j) {
        p0 += o[j] * w0[j];
        p1 += o[j] * w1[j];
    }
    if (g < 2) {
        float w2[8];
        *(float4*)&w2[0] = *(const float4*)(W3t + (g + 8) * FD + c * 8);
        *(float4*)&w2[4] = *(const float4*)(W3t + (g + 8) * FD + c * 8 + 4);
        #pragma unroll
        for (int j = 0; j < 8; ++j) p2 += o[j] * w2[j];
    }
    #pragma unroll
    for (int off = 1; off < 16; off <<= 1) {
        p0 += __shfl_xor(p0, off, 64);
        p1 += __shfl_xor(p1, off, 64);
        p2 += __shfl_xor(p2, off, 64);
    }
    if (c == 0) {
        float dself = dinv[w];                 // pre-scale bufC for layer-3
        float* op = outc + (size_t)w * OUTD;
        op[g] = p0 * dself;
        op[g + 4] = p1 * dself;
        if (g < 2) op[g + 8] = p2 * dself;
    }
}

// ---------------- layer-3 aggregation: one thread per (node, feature), no dinv ----------------

__global__ void k_spmm10(const int* __restrict__ rowptr, const uint2* __restrict__ ent,
        const float* __restrict__ tin, const float* __restrict__ bias,
        float* __restrict__ out, int n) {
    int t = blockIdx.x * blockDim.x + threadIdx.x;
    int node = t / OUTD;
    int c = t - node * OUTD;
    if (node >= n) return;
    int beg = rowptr[node], end = rowptr[node + 1];
    float acc = 0.0f;
    for (int e = beg; e < end; ++e) {
        uint2 en = ent[e];
        acc += __uint_as_float(en.y) * tin[(size_t)en.x * OUTD + c];
    }
    out[(size_t)node * OUTD + c] = acc + bias[c];
}

// ---------------- pooling + log_softmax (1 block/graph) ----------------

__global__ __launch_bounds__(256) void k_poolfin(const float* __restrict__ h,
        const int* __restrict__ gstart, float* __restrict__ out) {
    int g = blockIdx.x;
    int beg = gstart[g], end = gstart[g + 1];
    int tid = threadIdx.x;
    int lane = tid & 63, wv = tid >> 6;
    float acc[OUTD];
    #pragma unroll
    for (int c = 0; c < OUTD; ++c) acc[c] = 0.0f;
    for (int i = beg + tid; i < end; i += 256) {
        const float* hp = h + (size_t)i * OUTD;
        #pragma unroll
        for (int c = 0; c < OUTD; ++c) acc[c] += hp[c];
    }
    #pragma unroll
    for (int off = 32; off >= 1; off >>= 1)
        #pragma unroll
        for (int c = 0; c < OUTD; ++c) acc[c] += __shfl_down(acc[c], off, 64);
    __shared__ float ws[4][OUTD];
    if (lane == 0)
        #pragma unroll
        for (int c = 0; c < OUTD; ++c) ws[wv][c] = acc[c];
    __syncthreads();
    if (tid == 0) {
        float cf = fmaxf((float)(end - beg), 1.0f);
        float v[OUTD], m = -1e30f;
        #pragma unroll
        for (int c = 0; c < OUTD; ++c) {
            v[c] = (ws[0][c] + ws[1][c] + ws[2][c] + ws[3][c]) / cf;
            m = fmaxf(m, v[c]);
        }
        float s = 0.0f;
        #pragma unroll
        for (int c = 0; c < OUTD; ++c) s += expf(v[c] - m);
        float l = logf(s);
        #pragma unroll
        for (int c = 0; c < OUTD; ++c) out[g * OUTD + c] = v[c] - m - l;
    }
}

// ---------------- launcher ----------------

extern "C" void kernel_launch(void* const* d_in, const int* in_sizes, int n_in,
                              void* d_out, int out_size, void* d_ws, size_t ws_size,
                              hipStream_t stream) {
    const float* x   = (const float*)d_in[0];
    const int*   ei  = (const int*)d_in[1];
    const float* ew  = (const float*)d_in[2];
    const int*   bat = (const int*)d_in[3];
    const float* W1  = (const float*)d_in[4];
    const float* b1  = (const float*)d_in[5];
    const float* W2  = (const float*)d_in[6];
    const float* b2  = (const float*)d_in[7];
    const float* W3  = (const float*)d_in[8];
    const float* b3  = (const float*)d_in[9];
    float* out = (float*)d_out;

    const int* src = ei;
    const int* dst = ei + EE;

    char* p = (char*)d_ws;
    auto alloc = [&](size_t bytes) -> void* {
        void* r = (void*)p;
        p += (bytes + 255) & ~(size_t)255;
        return r;
    };
    int*            cnt2d  = (int*)  alloc((size_t)NBU * NBK * 4);
    int*            bbase  = (int*)  alloc((size_t)(NBU + 1) * 4);
    uint2*          rec    = (uint2*)alloc((size_t)EE * 8);
    unsigned short* rankb  = (unsigned short*)alloc((size_t)EE * 2);
    float*          dinv   = (float*)alloc((size_t)NN * 4);
    int*            rowptr = (int*)  alloc((size_t)(NN + 1) * 4);
    uint2*          ent    = (uint2*)alloc((size_t)(EE + NN) * 8);
    unsigned short* Wt1    = (unsigned short*)alloc((size_t)FD * FD * 2);
    unsigned short* Wt2    = (unsigned short*)alloc((size_t)FD * FD * 2);
    float*          W3t    = (float*)alloc((size_t)FD * OUTD * 4);
    unsigned short* hA     = (unsigned short*)alloc((size_t)NN * FD * 2);
    unsigned short* hB     = (unsigned short*)alloc((size_t)NN * FD * 2);
    float*          bufC   = (float*)alloc((size_t)NN * OUTD * 4);
    float*          bufD   = (float*)alloc((size_t)NN * OUTD * 4);
    int*            gstart = (int*)  alloc((size_t)(GG + 1) * 4);
    (void)ws_size; (void)in_sizes; (void)n_in; (void)out_size;

    const int B = 256;
    // 1: transposes || bucket histogram || graph bounds
    k_histbounds<<<TB + NBK + BB, B, 0, stream>>>(W1, W2, W3, Wt1, Wt2, W3t,
                                                  dst, cnt2d, bat, gstart);
    // 2: scatter (bucket-segmented records) || layer-1 GEMM
    k_scatgemm<<<NBK + GB, B, 0, stream>>>(src, dst, ew, cnt2d, bbase, rec, x, Wt1, hA);
    // 3: rank+fill: rowptr + dinv + full CSR
    k_rankfill<<<NBU, 1024, 0, stream>>>(rec, bbase, rowptr, dinv, ent, rankb);
    // 4: layer-1 aggregation (output pre-scaled by dinv)
    k_spmm_bf <<<(NN * 64 + B - 1) / B, B, 0, stream>>>(rowptr, ent, dinv, hA, b1, hB, NN);
    // 5: layer-2 transform
    k_gemm_bf <<<GB, B, 0, stream>>>(hB, Wt2, hA, NN);
    // 6: layer-2 aggregation + relu + W3 (output pre-scaled by dinv)
    k_spmm_w3 <<<(NN * 64 + B - 1) / B, B, 0, stream>>>(rowptr, ent, dinv, hA, b2, W3t, bufC, NN);
    // 7: layer-3 aggregation
    k_spmm10  <<<(NN * OUTD + B - 1) / B, B, 0, stream>>>(rowptr, ent, bufC, b3, bufD, NN);
    // 8: pool + log_softmax
    k_poolfin <<<GG, 256, 0, stream>>>(bufD, gstart, out);
}